// Round 1
// baseline (6221.374 us; speedup 1.0000x reference)
//
#include <hip/hip_runtime.h>

typedef _Float16 v8h __attribute__((ext_vector_type(8)));
typedef float v4f __attribute__((ext_vector_type(4)));
typedef unsigned int uint;

// ---- workspace layout (bytes) ----
#define OFF_BAR   0
#define OFF_AO0   4096
#define OFF_AO1   (OFF_AO0 + (1<<21))
#define OFF_AF0   (OFF_AO1 + (1<<21))
#define OFF_AF1   (OFF_AF0 + (1<<21))
#define OFF_W1    (OFF_AF1 + (1<<21))
#define OFF_W2    (OFF_W1 + (1<<21))
#define OFF_B1    (OFF_W2 + (1<<22))
#define OFF_B2    (OFF_B1 + 8192)

// Pack weights into MFMA B-fragment order:
// frag layout (16x16x32): n = nt*16 + (lane&15), k = k32*32 + (lane>>4)*8 + el
__global__ __launch_bounds__(256, 1)
void lstm_prep(const float* __restrict__ Whh1, const float* __restrict__ Wih2,
               const float* __restrict__ Whh2, const float* __restrict__ bih1,
               const float* __restrict__ bhh1, const float* __restrict__ bih2,
               const float* __restrict__ bhh2,
               _Float16* __restrict__ W1p, _Float16* __restrict__ W2p,
               float* __restrict__ bs1, float* __restrict__ bs2)
{
  const int total = 1048576 + 2097152 + 4096;
  for (int i = blockIdx.x*blockDim.x + threadIdx.x; i < total; i += gridDim.x*blockDim.x) {
    if (i < 1048576) {
      int nt = i >> 13, rem = i & 8191;
      int k32 = rem >> 9, c = rem & 511;
      int lane = c >> 3, el = c & 7;
      int n = nt*16 + (lane & 15);
      int k = k32*32 + (lane >> 4)*8 + el;
      W1p[i] = (_Float16)Whh1[n*512 + k];
    } else if (i < 3145728) {
      int j = i - 1048576;
      int nt = j >> 14, rem = j & 16383;
      int k32 = rem >> 9, c = rem & 511;
      int lane = c >> 3, el = c & 7;
      int n = nt*16 + (lane & 15);
      int k = k32*32 + (lane >> 4)*8 + el;
      float v = (k < 512) ? Wih2[n*512 + k] : Whh2[n*512 + (k - 512)];
      W2p[j] = (_Float16)v;
    } else {
      int n = i - 3145728;
      if (n < 2048) bs1[n] = bih1[n] + bhh1[n];
      else          bs2[n-2048] = bih2[n-2048] + bhh2[n-2048];
    }
  }
}

__device__ __forceinline__ float sigmoidf_(float z) { return 1.f / (1.f + __expf(-z)); }
__device__ __forceinline__ float tanhf_(float z)    { return 1.f - 2.f/(1.f + __expf(2.f*z)); }
__device__ __forceinline__ float dot4_(v4f a, v4f b){ return a[0]*b[0]+a[1]*b[1]+a[2]*b[2]+a[3]*b[3]; }

// agent-scope relaxed 16B fragment load (2x8B): proven-correct exchange primitive
__device__ __forceinline__ v8h ld_frag_dev(const _Float16* base, uint off) {
  union { unsigned long long u[2]; v8h h; } cv;
  const unsigned long long* q = (const unsigned long long*)(base + off);
  cv.u[0] = __hip_atomic_load(q,     __ATOMIC_RELAXED, __HIP_MEMORY_SCOPE_AGENT);
  cv.u[1] = __hip_atomic_load(q + 1, __ATOMIC_RELAXED, __HIP_MEMORY_SCOPE_AGENT);
  return cv.h;
}

// 256 blocks x 512 threads (8 waves), persistent, fused pipeline (162 rounds).
// R7 restructure: the B-tiling is gate-grouped (acc[i2][g*2+u] = gate g for the
// SAME (row,hcol)), so kh0 waves run the whole LSTM nonlinearity IN REGISTERS
// after the K-combine: no gred scatter/gather (132-stride bank conflicts gone),
// c-state lives in the GEMM waves' registers (16/lane), h goes to a small
// stash placed INSIDE the wave's own dump region (read-own-then-write-own =>
// no extra sync). 8 syncs/round -> 4. cw=(wv&1)^kh balances MFMA 384/SIMD
// (old cw=wv&1 put 512 on SIMDs 1,3 and 256 on 0,2). Bias + Wih1 fragments
// hoisted to registers (round-invariant).
// LDS (64KB): dump regions (cw*2+mtb)*4096 floats; stash for wave (cw,mtb) at
// region base, rows (b&31)*36 + col, 1152 floats, written post-combine.
__global__ __launch_bounds__(512, 2)
void lstm_main(const float* __restrict__ x, const float* __restrict__ Wih1,
               const float* __restrict__ Wl, const float* __restrict__ blv,
               _Float16* __restrict__ AO0, _Float16* __restrict__ AO1,
               _Float16* __restrict__ AF0, _Float16* __restrict__ AF1,
               const _Float16* __restrict__ W1, const _Float16* __restrict__ W2,
               const float* __restrict__ bs1, const float* __restrict__ bs2,
               int* __restrict__ bar, float* __restrict__ out)
{
  __shared__ float lred[16384];
  const int tid  = threadIdx.x;
  const int wv   = tid >> 6, lane = tid & 63;
  const int quad = lane >> 4, lc = lane & 15;
  const int kh   = wv >> 2;             // K half
  const int cw   = (wv & 1) ^ kh;       // cell; ^kh => each SIMD gets cell1+cell2
  const int mtb  = (wv >> 1) & 1;       // m-tile pair {mtb*2, mtb*2+1}
  const int bid  = blockIdx.x;
  const int jg   = bid >> 3;
  const int ht   = (bid & 7)*2 + (jg >> 4);   // XCD swizzle
  const int bt   = jg & 15;

  _Float16* const AOv[2] = {AO0, AO1};
  _Float16* const AFv[2] = {AF0, AF1};

  // store ownership (tid>=256): tid2 -> (b_loc, oct)
  const int tid2  = tid - 256;
  const int b_loc = (tid2 >= 0) ? (tid2 >> 2) : 0, oct = tid2 & 3;
  const int m     = b_loc & 15, mtile_e = bt*4 + (b_loc >> 4);

  int ntg_[8];
  #pragma unroll
  for (int tt = 0; tt < 8; tt++) ntg_[tt] = (tt>>1)*32 + ht*2 + (tt&1);

  // round-invariant per-lane constants for the in-register epilogue (kh0 only)
  float b1r[8], b2r[8];   // [g*2+u]
  v4f   w1r[4][2];        // Wih1 rows for the lane's 8 gate-cols
  if (!kh) {
    #pragma unroll
    for (int g = 0; g < 4; g++)
      #pragma unroll
      for (int u = 0; u < 2; u++) {
        const int col = g*512 + ht*32 + u*16 + lc;
        b1r[g*2+u] = bs1[col];
        b2r[g*2+u] = bs2[col];
        w1r[g][u]  = *(const v4f*)(Wih1 + (size_t)col*4);
      }
  }

  // c-state: 16 values/lane on kh0 waves: (i2,u,rr) ->
  // row=(mtb*2+i2)*16+quad*4+rr, hcol=ht*32+u*16+lc, cell=cw
  float cst[16];
  #pragma unroll
  for (int i = 0; i < 16; i++) cst[i] = 0.f;

  const int rbase = (cw*2 + mtb) * 4096;

  for (int r = 0; r < 162; r++) {
    const bool p1 = r < 129;
    const int  f  = r - 129;
    const int  wp = p1 ? (r & 1) : (f & 1);   // write parity
    const int  rp = wp ^ 1;                   // read parity
    const _Float16* A1 = p1 ? AOv[rp] : AFv[rp];
    const _Float16* A2 = AOv[rp];
    const bool skip1 = (r == 128 || r == 161);
    const bool skip2 = (r == 0   || r == 129);

    // ---- this wave's GEMM ----
    const _Float16* Ac = cw ? A2 : A1;
    const _Float16* Bc = cw ? W2 : (p1 ? W1 : W2);
    const int wk   = cw ? 32 : (p1 ? 16 : 32);
    const int half = cw ? 16 : (p1 ? 8 : 16);
    const int ch0  = kh * half;

    v4f acc[2][8];
    #pragma unroll
    for (int i2 = 0; i2 < 2; i2++)
      #pragma unroll
      for (int tt = 0; tt < 8; tt++) acc[i2][tt] = (v4f){0,0,0,0};

    uint aoff[2];
    #pragma unroll
    for (int i2 = 0; i2 < 2; i2++)
      aoff[i2] = (uint)(((bt*4 + mtb*2 + i2)*32 + ch0)*512 + lane*8);
    uint boff[8];
    #pragma unroll
    for (int tt = 0; tt < 8; tt++)
      boff[tt] = (uint)((ntg_[tt]*wk + ch0)*512 + lane*8);

    #pragma unroll 4
    for (int cc = 0; cc < half; cc++) {
      v8h av[2];
      #pragma unroll
      for (int i2 = 0; i2 < 2; i2++)
        av[i2] = ld_frag_dev(Ac, aoff[i2] + cc*512);
      #pragma unroll
      for (int tt = 0; tt < 8; tt++) {
        v8h bv = *(const v8h*)(Bc + boff[tt] + cc*512);
        #pragma unroll
        for (int i2 = 0; i2 < 2; i2++)
          acc[i2][tt] = __builtin_amdgcn_mfma_f32_16x16x32_f16(av[i2], bv, acc[i2][tt], 0, 0, 0);
      }
    }

    // ---- K-reduce: kh=1 waves dump ----
    if (kh) {
      #pragma unroll
      for (int i2 = 0; i2 < 2; i2++)
        #pragma unroll
        for (int tt = 0; tt < 8; tt++)
          *(v4f*)&lred[rbase + ((i2*8 + tt)*64 + lane)*4] = acc[i2][tt];
    }
    __syncthreads();

    // ---- kh=0: combine + IN-REGISTER epilogue -> stash (own region) ----
    if (!kh) {
      const bool xterm = (cw == 0) && p1 && (r < 128);
      v4f xr[2][4];
      if (xterm) {                       // issue x loads early (overlap combine)
        #pragma unroll
        for (int i2 = 0; i2 < 2; i2++)
          #pragma unroll
          for (int rr = 0; rr < 4; rr++)
            xr[i2][rr] = *(const v4f*)(x + ((size_t)r*1024 + bt*64
                              + (mtb*2 + i2)*16 + quad*4 + rr)*4);
      }
      #pragma unroll
      for (int i2 = 0; i2 < 2; i2++)
        #pragma unroll
        for (int tt = 0; tt < 8; tt++)
          acc[i2][tt] += *(const v4f*)&lred[rbase + ((i2*8 + tt)*64 + lane)*4];

      const bool skipc = cw ? skip2 : skip1;
      if (!skipc) {
        const bool useb1 = (cw == 0) && p1;
        #pragma unroll
        for (int i2 = 0; i2 < 2; i2++)
          #pragma unroll
          for (int u = 0; u < 2; u++)
            #pragma unroll
            for (int rr = 0; rr < 4; rr++) {
              float gi = acc[i2][0+u][rr] + (useb1 ? b1r[0+u] : b2r[0+u]);
              float gf = acc[i2][2+u][rr] + (useb1 ? b1r[2+u] : b2r[2+u]);
              float gg = acc[i2][4+u][rr] + (useb1 ? b1r[4+u] : b2r[4+u]);
              float go = acc[i2][6+u][rr] + (useb1 ? b1r[6+u] : b2r[6+u]);
              if (xterm) {
                gi += dot4_(xr[i2][rr], w1r[0][u]);
                gf += dot4_(xr[i2][rr], w1r[1][u]);
                gg += dot4_(xr[i2][rr], w1r[2][u]);
                go += dot4_(xr[i2][rr], w1r[3][u]);
              }
              const float ig = sigmoidf_(gi), fg = sigmoidf_(gf);
              const float g2 = tanhf_(gg),    og = sigmoidf_(go);
              const int ci = (i2*2 + u)*4 + rr;
              const float c = fg*cst[ci] + ig*g2;
              cst[ci] = c;
              // stash inside OWN region (read above, write now: race-free)
              lred[rbase + (i2*16 + quad*4 + rr)*36 + u*16 + lc] = og * tanhf_(c);
            }
      }
    }
    __syncthreads();

    // ---- stores from stash (tid>=256 = kh1 waves) + out-projection (tid<256) ----
    if (tid >= 256) {
      union { _Float16 h8[8]; unsigned long long u[2]; } hu;
      auto st16 = [&](_Float16* bp, int chunk) {
        unsigned long long* p = (unsigned long long*)
          (bp + (((size_t)(mtile_e*32 + chunk)) << 9) + (oct*16 + m)*8);
        __hip_atomic_store(p,     hu.u[0], __ATOMIC_RELAXED, __HIP_MEMORY_SCOPE_AGENT);
        __hip_atomic_store(p + 1, hu.u[1], __ATOMIC_RELAXED, __HIP_MEMORY_SCOPE_AGENT);
      };
      if (!skip1) {   // cell1 h: regions 0/1, rows (b&31)
        const float* sp = &lred[(b_loc >> 5)*4096 + (b_loc & 31)*36 + oct*8];
        v4f h0 = *(const v4f*)sp, h1v = *(const v4f*)(sp + 4);
        #pragma unroll
        for (int j = 0; j < 4; j++) { hu.h8[j] = (_Float16)h0[j]; hu.h8[4+j] = (_Float16)h1v[j]; }
        if (p1) {
          st16(AOv[wp], ht);
          if (r == 127) st16(AFv[1], 16 + ht);   // h1(127) for f=0's h1f-GEMM
        } else {
          st16(AFv[wp], 16 + ht);
          st16(AOv[wp], ht);
        }
      }
      if (!skip2) {   // cell2 h: regions 2/3
        const float* sp = &lred[(2 + (b_loc >> 5))*4096 + (b_loc & 31)*36 + oct*8];
        v4f h0 = *(const v4f*)sp, h1v = *(const v4f*)(sp + 4);
        #pragma unroll
        for (int j = 0; j < 4; j++) { hu.h8[j] = (_Float16)h0[j]; hu.h8[4+j] = (_Float16)h1v[j]; }
        st16(AOv[wp], 16 + ht);
        if (r == 128) { st16(AFv[0], ht); st16(AFv[1], ht); }   // tmp = h2(127)
      }
    }
    if (tid < 256 && !p1 && r >= 130) {  // out(s) = h2f(s) @ Wl^T + bl, s = r-130
      const int s = r - 130;
      int bb = tid >> 2, o = tid & 3;
      float sa = (ht == 0) ? blv[o] : 0.f;
      const float* wl = Wl + (size_t)o*512 + ht*32;
      const float* sp = &lred[(2 + (bb >> 5))*4096 + (bb & 31)*36];
      #pragma unroll
      for (int jj = 0; jj < 32; jj++) sa += sp[jj] * wl[jj];
      atomicAdd(&out[(((size_t)s*1024) + bt*64 + bb)*4 + o], sa);
    }
    __syncthreads();

    // ---- per-bt-group barrier: agent-relaxed add + relaxed poll ----
    if (tid == 0) {
      int* ctr = bar + bt*32;          // 128B-spaced counters
      __hip_atomic_fetch_add(ctr, 1, __ATOMIC_RELAXED, __HIP_MEMORY_SCOPE_AGENT);
      const int target = 16*(r+1);
      while (__hip_atomic_load(ctr, __ATOMIC_RELAXED, __HIP_MEMORY_SCOPE_AGENT) < target)
        __builtin_amdgcn_s_sleep(1);
    }
    __syncthreads();
  }
}

extern "C" void kernel_launch(void* const* d_in, const int* in_sizes, int n_in,
                              void* d_out, int out_size, void* d_ws, size_t ws_size,
                              hipStream_t stream) {
  const float* x    = (const float*)d_in[0];
  const float* Wih1 = (const float*)d_in[1];
  const float* Whh1 = (const float*)d_in[2];
  const float* bih1 = (const float*)d_in[3];
  const float* bhh1 = (const float*)d_in[4];
  const float* Wih2 = (const float*)d_in[5];
  const float* Whh2 = (const float*)d_in[6];
  const float* bih2 = (const float*)d_in[7];
  const float* bhh2 = (const float*)d_in[8];
  const float* Wl   = (const float*)d_in[9];
  const float* bl   = (const float*)d_in[10];

  char* ws = (char*)d_ws;
  int*      bar = (int*)(ws + OFF_BAR);
  _Float16* AO0 = (_Float16*)(ws + OFF_AO0);
  _Float16* AO1 = (_Float16*)(ws + OFF_AO1);
  _Float16* AF0 = (_Float16*)(ws + OFF_AF0);
  _Float16* AF1 = (_Float16*)(ws + OFF_AF1);
  _Float16* W1p = (_Float16*)(ws + OFF_W1);
  _Float16* W2p = (_Float16*)(ws + OFF_W2);
  float*    bs1 = (float*)(ws + OFF_B1);
  float*    bs2 = (float*)(ws + OFF_B2);

  // zero barrier + state buffers (h,c start at 0); zero out (atomic accumulation)
  hipMemsetAsync(ws, 0, (size_t)OFF_W1, stream);
  hipMemsetAsync(d_out, 0, (size_t)out_size * sizeof(float), stream);

  lstm_prep<<<2048, 256, 0, stream>>>(Whh1, Wih2, Whh2, bih1, bhh1, bih2, bhh2,
                                      W1p, W2p, bs1, bs2);
  lstm_main<<<256, 512, 0, stream>>>(x, Wih1, Wl, bl, AO0, AO1, AF0, AF1,
                                     W1p, W2p, bs1, bs2, bar, (float*)d_out);
}

// Round 2
// 3096.830 us; speedup vs baseline: 2.0089x; 2.0089x over previous
//
#include <hip/hip_runtime.h>

typedef _Float16 v8h __attribute__((ext_vector_type(8)));
typedef float v4f __attribute__((ext_vector_type(4)));
typedef unsigned int uint;

// ---- workspace layout (bytes) ----
#define OFF_BAR   0
#define OFF_AO0   4096
#define OFF_AO1   (OFF_AO0 + (1<<21))
#define OFF_AF0   (OFF_AO1 + (1<<21))
#define OFF_AF1   (OFF_AF0 + (1<<21))
#define OFF_W1    (OFF_AF1 + (1<<21))
#define OFF_W2    (OFF_W1 + (1<<21))
#define OFF_B1    (OFF_W2 + (1<<22))
#define OFF_B2    (OFF_B1 + 8192)

// Pack weights into MFMA B-fragment order:
// frag layout (16x16x32): n = nt*16 + (lane&15), k = k32*32 + (lane>>4)*8 + el
__global__ __launch_bounds__(256, 1)
void lstm_prep(const float* __restrict__ Whh1, const float* __restrict__ Wih2,
               const float* __restrict__ Whh2, const float* __restrict__ bih1,
               const float* __restrict__ bhh1, const float* __restrict__ bih2,
               const float* __restrict__ bhh2,
               _Float16* __restrict__ W1p, _Float16* __restrict__ W2p,
               float* __restrict__ bs1, float* __restrict__ bs2)
{
  const int total = 1048576 + 2097152 + 4096;
  for (int i = blockIdx.x*blockDim.x + threadIdx.x; i < total; i += gridDim.x*blockDim.x) {
    if (i < 1048576) {
      int nt = i >> 13, rem = i & 8191;
      int k32 = rem >> 9, c = rem & 511;
      int lane = c >> 3, el = c & 7;
      int n = nt*16 + (lane & 15);
      int k = k32*32 + (lane >> 4)*8 + el;
      W1p[i] = (_Float16)Whh1[n*512 + k];
    } else if (i < 3145728) {
      int j = i - 1048576;
      int nt = j >> 14, rem = j & 16383;
      int k32 = rem >> 9, c = rem & 511;
      int lane = c >> 3, el = c & 7;
      int n = nt*16 + (lane & 15);
      int k = k32*32 + (lane >> 4)*8 + el;
      float v = (k < 512) ? Wih2[n*512 + k] : Whh2[n*512 + (k - 512)];
      W2p[j] = (_Float16)v;
    } else {
      int n = i - 3145728;
      if (n < 2048) bs1[n] = bih1[n] + bhh1[n];
      else          bs2[n-2048] = bih2[n-2048] + bhh2[n-2048];
    }
  }
}

__device__ __forceinline__ float sigmoidf_(float z) { return 1.f / (1.f + __expf(-z)); }
__device__ __forceinline__ float tanhf_(float z)    { return 1.f - 2.f/(1.f + __expf(2.f*z)); }

// agent-scope relaxed 16B fragment load (2x8B): proven-correct exchange primitive
__device__ __forceinline__ v8h ld_frag_dev(const _Float16* base, uint off) {
  union { unsigned long long u[2]; v8h h; } cv;
  const unsigned long long* q = (const unsigned long long*)(base + off);
  cv.u[0] = __hip_atomic_load(q,     __ATOMIC_RELAXED, __HIP_MEMORY_SCOPE_AGENT);
  cv.u[1] = __hip_atomic_load(q + 1, __ATOMIC_RELAXED, __HIP_MEMORY_SCOPE_AGENT);
  return cv.h;
}

// 256 blocks x 512 threads (8 waves, 2/SIMD), persistent, fused pipeline (162 rounds).
// R8 = proven R6 structure + ONE change: cw = (wv&1)^kh SIMD-balances MFMA.
// Old cw=wv&1 gave SIMDs 1,3 two cell2-waves (256 MFMA each) and SIMDs 0,2 two
// cell1-waves (128 MFMA in phase1) -> 2.13us straggler SIMD. XOR with kh gives
// every SIMD one cell1 + one cell2 wave (384 MFMA balanced). Dump-region pairing
// (cw*2+mtb) still has exactly one kh0 + one kh1 wave per region; epilogue /
// scatter / store logic untouched (kh0 waves keep their old cw).
// R7 lesson: gred bank conflicts are fully hidden at 4 waves/SIMD; the kernel is
// latency-chain-bound (46k cyc/round vs 2.5k MFMA floor). Do NOT concentrate
// epilogue work on fewer threads.
// LDS (64KB): dump regions (cell*2+mtb)*4096 floats; gred 64x132 at [0,8448);
// stash 64x36 fp32 at [8448,10752) — lifetimes strictly sequenced by syncs.
__global__ __launch_bounds__(512, 2)
void lstm_main(const float* __restrict__ x, const float* __restrict__ Wih1,
               const float* __restrict__ Wl, const float* __restrict__ blv,
               _Float16* __restrict__ AO0, _Float16* __restrict__ AO1,
               _Float16* __restrict__ AF0, _Float16* __restrict__ AF1,
               const _Float16* __restrict__ W1, const _Float16* __restrict__ W2,
               const float* __restrict__ bs1, const float* __restrict__ bs2,
               int* __restrict__ bar, float* __restrict__ out)
{
  __shared__ float lred[16384];
  const int tid  = threadIdx.x;
  const int wv   = tid >> 6, lane = tid & 63;
  const int quad = lane >> 4, lc = lane & 15;
  const int kh   = wv >> 2;          // K half
  const int cw   = (wv & 1) ^ kh;    // cell; ^kh => each SIMD gets cell1+cell2
  const int mtb  = (wv >> 1) & 1;    // m-tile pair {mtb*2, mtb*2+1}
  const int bid  = blockIdx.x;
  const int jg   = bid >> 3;
  const int ht   = (bid & 7)*2 + (jg >> 4);   // XCD swizzle
  const int bt   = jg & 15;

  _Float16* const AOv[2] = {AO0, AO1};
  _Float16* const AFv[2] = {AF0, AF1};

  // epilogue-compute ownership (all 512): row erow, cols enib*4..+3
  const int erow = tid >> 3, enib = tid & 7;
  // store ownership (tid>=256): tid2 -> (b_loc, oct)
  const int tid2  = tid - 256;
  const int b_loc = (tid2 >= 0) ? (tid2 >> 2) : 0, oct = tid2 & 3;
  const int m     = b_loc & 15, mtile_e = bt*4 + (b_loc >> 4);
  const int STASH = 8448;

  int ntg_[8];
  #pragma unroll
  for (int tt = 0; tt < 8; tt++) ntg_[tt] = (tt>>1)*32 + ht*2 + (tt&1);

  float c1s[4], c2s[4];
  #pragma unroll
  for (int i = 0; i < 4; i++) { c1s[i] = 0.f; c2s[i] = 0.f; }

  for (int r = 0; r < 162; r++) {
    const bool p1 = r < 129;
    const int  f  = r - 129;
    const int  wp = p1 ? (r & 1) : (f & 1);   // write parity
    const int  rp = wp ^ 1;                   // read parity
    const _Float16* A1 = p1 ? AOv[rp] : AFv[rp];
    const _Float16* A2 = AOv[rp];
    const bool skip1 = (r == 128 || r == 161);
    const bool skip2 = (r == 0   || r == 129);

    // ---- this wave's GEMM ----
    const _Float16* Ac = cw ? A2 : A1;
    const _Float16* Bc = cw ? W2 : (p1 ? W1 : W2);
    const int wk   = cw ? 32 : (p1 ? 16 : 32);
    const int half = cw ? 16 : (p1 ? 8 : 16);
    const int ch0  = kh * half;

    v4f acc[2][8];
    #pragma unroll
    for (int i2 = 0; i2 < 2; i2++)
      #pragma unroll
      for (int tt = 0; tt < 8; tt++) acc[i2][tt] = (v4f){0,0,0,0};

    uint aoff[2];
    #pragma unroll
    for (int i2 = 0; i2 < 2; i2++)
      aoff[i2] = (uint)(((bt*4 + mtb*2 + i2)*32 + ch0)*512 + lane*8);
    uint boff[8];
    #pragma unroll
    for (int tt = 0; tt < 8; tt++)
      boff[tt] = (uint)((ntg_[tt]*wk + ch0)*512 + lane*8);

    #pragma unroll 4
    for (int cc = 0; cc < half; cc++) {
      v8h av[2];
      #pragma unroll
      for (int i2 = 0; i2 < 2; i2++)
        av[i2] = ld_frag_dev(Ac, aoff[i2] + cc*512);
      #pragma unroll
      for (int tt = 0; tt < 8; tt++) {
        v8h bv = *(const v8h*)(Bc + boff[tt] + cc*512);
        #pragma unroll
        for (int i2 = 0; i2 < 2; i2++)
          acc[i2][tt] = __builtin_amdgcn_mfma_f32_16x16x32_f16(av[i2], bv, acc[i2][tt], 0, 0, 0);
      }
    }

    // ---- K-reduce: kh=1 waves dump, kh=0 waves combine ----
    const int rbase = (cw*2 + mtb) * 4096;
    if (kh) {
      #pragma unroll
      for (int i2 = 0; i2 < 2; i2++)
        #pragma unroll
        for (int tt = 0; tt < 8; tt++)
          *(v4f*)&lred[rbase + ((i2*8 + tt)*64 + lane)*4] = acc[i2][tt];
    }
    __syncthreads();
    if (!kh) {
      #pragma unroll
      for (int i2 = 0; i2 < 2; i2++)
        #pragma unroll
        for (int tt = 0; tt < 8; tt++)
          acc[i2][tt] += *(const v4f*)&lred[rbase + ((i2*8 + tt)*64 + lane)*4];
    }
    __syncthreads();

    // ---- scatter cell1 into gred (stride 132) by waves wv0,wv2 ----
    if (!kh && cw == 0) {
      #pragma unroll
      for (int i2 = 0; i2 < 2; i2++)
        #pragma unroll
        for (int tt = 0; tt < 8; tt++) {
          int row = (mtb*2 + i2)*16 + quad*4;
          int col = tt*16 + lc;
          #pragma unroll
          for (int rr = 0; rr < 4; rr++) lred[(row + rr)*132 + col] = acc[i2][tt][rr];
        }
    }
    __syncthreads();

    // ================= epilogue cell1 (all 512 threads) =================
    {
      const float* bsx = p1 ? bs1 : bs2;
      float g[4][4];
      #pragma unroll
      for (int g4 = 0; g4 < 4; g4++) {
        v4f gv = *(const v4f*)&lred[erow*132 + g4*32 + enib*4];
        v4f bv = *(const v4f*)&bsx[g4*512 + ht*32 + enib*4];
        #pragma unroll
        for (int j = 0; j < 4; j++) g[g4][j] = gv[j] + bv[j];
      }
      if (p1 && r < 128) {             // + x @ Wih1^T (K=4, exact fp32)
        const v4f xv = *(const v4f*)(x + ((size_t)r*1024 + bt*64 + erow)*4);
        #pragma unroll
        for (int g4 = 0; g4 < 4; g4++)
          #pragma unroll
          for (int j = 0; j < 4; j++) {
            int hh = ht*32 + enib*4 + j;
            const v4f w = *(const v4f*)(Wih1 + (size_t)(g4*512 + hh)*4);
            g[g4][j] += xv[0]*w[0] + xv[1]*w[1] + xv[2]*w[2] + xv[3]*w[3];
          }
      }
      if (!skip1) {
        v4f hf;
        #pragma unroll
        for (int j = 0; j < 4; j++) {
          float ig = sigmoidf_(g[0][j]), fg = sigmoidf_(g[1][j]);
          float gg = tanhf_(g[2][j]),    og = sigmoidf_(g[3][j]);
          float c = fg*c1s[j] + ig*gg;
          c1s[j] = c;
          hf[j] = og * tanhf_(c);
        }
        *(v4f*)&lred[STASH + erow*36 + enib*4] = hf;
      }
    }
    __syncthreads();

    // ---- concurrent: store h1 (tid>=256, from stash) + scatter cell2 (wv1,wv3) ----
    if (tid >= 256 && !skip1) {
      v4f h0 = *(const v4f*)&lred[STASH + b_loc*36 + oct*8];
      v4f h1 = *(const v4f*)&lred[STASH + b_loc*36 + oct*8 + 4];
      union { _Float16 h8[8]; unsigned long long u[2]; } hu;
      #pragma unroll
      for (int j = 0; j < 4; j++) { hu.h8[j] = (_Float16)h0[j]; hu.h8[4+j] = (_Float16)h1[j]; }
      auto st16 = [&](_Float16* bp, int chunk) {
        unsigned long long* p = (unsigned long long*)
          (bp + (((size_t)(mtile_e*32 + chunk)) << 9) + (oct*16 + m)*8);
        __hip_atomic_store(p,     hu.u[0], __ATOMIC_RELAXED, __HIP_MEMORY_SCOPE_AGENT);
        __hip_atomic_store(p + 1, hu.u[1], __ATOMIC_RELAXED, __HIP_MEMORY_SCOPE_AGENT);
      };
      if (p1) {
        st16(AOv[wp], ht);
        if (r == 127) st16(AFv[1], 16 + ht);   // h1(127) for f=0's h1f-GEMM
      } else {
        st16(AFv[wp], 16 + ht);
        st16(AOv[wp], ht);
      }
    }
    if (!kh && cw == 1) {              // scatter cell2 into gred
      #pragma unroll
      for (int i2 = 0; i2 < 2; i2++)
        #pragma unroll
        for (int tt = 0; tt < 8; tt++) {
          int row = (mtb*2 + i2)*16 + quad*4;
          int col = tt*16 + lc;
          #pragma unroll
          for (int rr = 0; rr < 4; rr++) lred[(row + rr)*132 + col] = acc[i2][tt][rr];
        }
    }
    __syncthreads();

    // ================= epilogue cell2 (all 512 threads) =================
    {
      float g[4][4];
      #pragma unroll
      for (int g4 = 0; g4 < 4; g4++) {
        v4f gv = *(const v4f*)&lred[erow*132 + g4*32 + enib*4];
        v4f bv = *(const v4f*)&bs2[g4*512 + ht*32 + enib*4];
        #pragma unroll
        for (int j = 0; j < 4; j++) g[g4][j] = gv[j] + bv[j];
      }
      if (!skip2) {
        v4f hf;
        #pragma unroll
        for (int j = 0; j < 4; j++) {
          float ig = sigmoidf_(g[0][j]), fg = sigmoidf_(g[1][j]);
          float gg = tanhf_(g[2][j]),    og = sigmoidf_(g[3][j]);
          float c = fg*c2s[j] + ig*gg;
          c2s[j] = c;
          hf[j] = og * tanhf_(c);
        }
        *(v4f*)&lred[STASH + erow*36 + enib*4] = hf;
      }
    }
    __syncthreads();

    // ---- store h2 (tid>=256) + out-projection (tid<256, phase2) ----
    if (tid >= 256 && !skip2) {
      v4f h0 = *(const v4f*)&lred[STASH + b_loc*36 + oct*8];
      v4f h1 = *(const v4f*)&lred[STASH + b_loc*36 + oct*8 + 4];
      union { _Float16 h8[8]; unsigned long long u[2]; } hu;
      #pragma unroll
      for (int j = 0; j < 4; j++) { hu.h8[j] = (_Float16)h0[j]; hu.h8[4+j] = (_Float16)h1[j]; }
      auto st16 = [&](_Float16* bp, int chunk) {
        unsigned long long* p = (unsigned long long*)
          (bp + (((size_t)(mtile_e*32 + chunk)) << 9) + (oct*16 + m)*8);
        __hip_atomic_store(p,     hu.u[0], __ATOMIC_RELAXED, __HIP_MEMORY_SCOPE_AGENT);
        __hip_atomic_store(p + 1, hu.u[1], __ATOMIC_RELAXED, __HIP_MEMORY_SCOPE_AGENT);
      };
      st16(AOv[wp], 16 + ht);
      if (r == 128) { st16(AFv[0], ht); st16(AFv[1], ht); }   // tmp = h2(127)
    }
    if (tid < 256 && !p1 && r >= 130) {  // out(s) = h2f(s) @ Wl^T + bl, s = r-130
      const int s = r - 130;
      int bb = tid >> 2, o = tid & 3;
      float sa = (ht == 0) ? blv[o] : 0.f;
      const float* wl = Wl + (size_t)o*512 + ht*32;
      #pragma unroll
      for (int jj = 0; jj < 32; jj++) sa += lred[STASH + bb*36 + jj] * wl[jj];
      atomicAdd(&out[(((size_t)s*1024) + bt*64 + bb)*4 + o], sa);
    }
    __syncthreads();

    // ---- per-bt-group barrier: agent-relaxed add + relaxed poll ----
    if (tid == 0) {
      int* ctr = bar + bt*32;          // 128B-spaced counters
      __hip_atomic_fetch_add(ctr, 1, __ATOMIC_RELAXED, __HIP_MEMORY_SCOPE_AGENT);
      const int target = 16*(r+1);
      while (__hip_atomic_load(ctr, __ATOMIC_RELAXED, __HIP_MEMORY_SCOPE_AGENT) < target)
        __builtin_amdgcn_s_sleep(1);
    }
    __syncthreads();
  }
}

extern "C" void kernel_launch(void* const* d_in, const int* in_sizes, int n_in,
                              void* d_out, int out_size, void* d_ws, size_t ws_size,
                              hipStream_t stream) {
  const float* x    = (const float*)d_in[0];
  const float* Wih1 = (const float*)d_in[1];
  const float* Whh1 = (const float*)d_in[2];
  const float* bih1 = (const float*)d_in[3];
  const float* bhh1 = (const float*)d_in[4];
  const float* Wih2 = (const float*)d_in[5];
  const float* Whh2 = (const float*)d_in[6];
  const float* bih2 = (const float*)d_in[7];
  const float* bhh2 = (const float*)d_in[8];
  const float* Wl   = (const float*)d_in[9];
  const float* bl   = (const float*)d_in[10];

  char* ws = (char*)d_ws;
  int*      bar = (int*)(ws + OFF_BAR);
  _Float16* AO0 = (_Float16*)(ws + OFF_AO0);
  _Float16* AO1 = (_Float16*)(ws + OFF_AO1);
  _Float16* AF0 = (_Float16*)(ws + OFF_AF0);
  _Float16* AF1 = (_Float16*)(ws + OFF_AF1);
  _Float16* W1p = (_Float16*)(ws + OFF_W1);
  _Float16* W2p = (_Float16*)(ws + OFF_W2);
  float*    bs1 = (float*)(ws + OFF_B1);
  float*    bs2 = (float*)(ws + OFF_B2);

  // zero barrier + state buffers (h,c start at 0); zero out (atomic accumulation)
  hipMemsetAsync(ws, 0, (size_t)OFF_W1, stream);
  hipMemsetAsync(d_out, 0, (size_t)out_size * sizeof(float), stream);

  lstm_prep<<<2048, 256, 0, stream>>>(Whh1, Wih2, Whh2, bih1, bhh1, bih2, bhh2,
                                      W1p, W2p, bs1, bs2);
  lstm_main<<<256, 512, 0, stream>>>(x, Wih1, Wl, bl, AO0, AO1, AF0, AF1,
                                     W1p, W2p, bs1, bs2, bar, (float*)d_out);
}

// Round 3
// 2918.509 us; speedup vs baseline: 2.1317x; 1.0611x over previous
//
#include <hip/hip_runtime.h>

typedef _Float16 v8h __attribute__((ext_vector_type(8)));
typedef float v4f __attribute__((ext_vector_type(4)));
typedef unsigned int uint;

// ---- workspace layout (bytes) ----
#define OFF_BAR   0
#define OFF_AO0   4096
#define OFF_AO1   (OFF_AO0 + (1<<21))
#define OFF_AF0   (OFF_AO1 + (1<<21))
#define OFF_AF1   (OFF_AF0 + (1<<21))
#define OFF_W1    (OFF_AF1 + (1<<21))
#define OFF_W2    (OFF_W1 + (1<<21))
#define OFF_B1    (OFF_W2 + (1<<22))
#define OFF_B2    (OFF_B1 + 8192)

// Pack weights into MFMA B-fragment order:
// frag layout (16x16x32): n = nt*16 + (lane&15), k = k32*32 + (lane>>4)*8 + el
__global__ __launch_bounds__(256, 1)
void lstm_prep(const float* __restrict__ Whh1, const float* __restrict__ Wih2,
               const float* __restrict__ Whh2, const float* __restrict__ bih1,
               const float* __restrict__ bhh1, const float* __restrict__ bih2,
               const float* __restrict__ bhh2,
               _Float16* __restrict__ W1p, _Float16* __restrict__ W2p,
               float* __restrict__ bs1, float* __restrict__ bs2)
{
  const int total = 1048576 + 2097152 + 4096;
  for (int i = blockIdx.x*blockDim.x + threadIdx.x; i < total; i += gridDim.x*blockDim.x) {
    if (i < 1048576) {
      int nt = i >> 13, rem = i & 8191;
      int k32 = rem >> 9, c = rem & 511;
      int lane = c >> 3, el = c & 7;
      int n = nt*16 + (lane & 15);
      int k = k32*32 + (lane >> 4)*8 + el;
      W1p[i] = (_Float16)Whh1[n*512 + k];
    } else if (i < 3145728) {
      int j = i - 1048576;
      int nt = j >> 14, rem = j & 16383;
      int k32 = rem >> 9, c = rem & 511;
      int lane = c >> 3, el = c & 7;
      int n = nt*16 + (lane & 15);
      int k = k32*32 + (lane >> 4)*8 + el;
      float v = (k < 512) ? Wih2[n*512 + k] : Whh2[n*512 + (k - 512)];
      W2p[j] = (_Float16)v;
    } else {
      int n = i - 3145728;
      if (n < 2048) bs1[n] = bih1[n] + bhh1[n];
      else          bs2[n-2048] = bih2[n-2048] + bhh2[n-2048];
    }
  }
}

__device__ __forceinline__ float sigmoidf_(float z) { return 1.f / (1.f + __expf(-z)); }
__device__ __forceinline__ float tanhf_(float z)    { return 1.f - 2.f/(1.f + __expf(2.f*z)); }

// agent-scope relaxed 16B fragment load (2x8B): proven-correct exchange primitive
__device__ __forceinline__ v8h ld_frag_dev(const _Float16* base, uint off) {
  union { unsigned long long u[2]; v8h h; } cv;
  const unsigned long long* q = (const unsigned long long*)(base + off);
  cv.u[0] = __hip_atomic_load(q,     __ATOMIC_RELAXED, __HIP_MEMORY_SCOPE_AGENT);
  cv.u[1] = __hip_atomic_load(q + 1, __ATOMIC_RELAXED, __HIP_MEMORY_SCOPE_AGENT);
  return cv.h;
}

// R9: 512 blocks x 256 threads (4 waves), persistent, 162 rounds.
// Same per-thread work / per-wave MFMA / total traffic as the proven 256x512
// kernel, but each block now owns 32 batch rows x 32 gate-cols, so each CU
// hosts TWO blocks from DIFFERENT bt-groups (independent barrier domains).
// Rationale (R8 counters): at 1 block/CU all 8 waves stall together at the
// global barrier + A-load latency window (~60% of the ~25k-cyc round, chip
// downclocked to ~1.3GHz). Two independent blocks/CU let one block's waves
// issue while the other stalls. LDS padded to 56KB to FORCE <=2 blocks/CU so
// all 512 persistent blocks are co-resident (deadlock safety).
// Index map: jg=bid>>3; ht=(bid&7)*2+(jg&1); bt=jg>>1  -> co-resident pair
// (bid, bid+256) has same ht, bt differing by 16 => different barrier groups.
// Waves: kh=wv>>1 (K half), cw=(wv&1)^kh (cell; each SIMD-pair balanced).
// LDS: dump regions cw*4096 floats [0,8192); gred 32x132 at [0,4224);
// stash 32x36 fp32 at [8448,9600) — lifetimes strictly sequenced by syncs.
__global__ __launch_bounds__(256, 2)
void lstm_main(const float* __restrict__ x, const float* __restrict__ Wih1,
               const float* __restrict__ Wl, const float* __restrict__ blv,
               _Float16* __restrict__ AO0, _Float16* __restrict__ AO1,
               _Float16* __restrict__ AF0, _Float16* __restrict__ AF1,
               const _Float16* __restrict__ W1, const _Float16* __restrict__ W2,
               const float* __restrict__ bs1, const float* __restrict__ bs2,
               int* __restrict__ bar, float* __restrict__ out)
{
  __shared__ float lred[14336];        // 56KB: forces <=2 blocks/CU
  const int tid  = threadIdx.x;
  const int wv   = tid >> 6, lane = tid & 63;
  const int quad = lane >> 4, lc = lane & 15;
  const int kh   = wv >> 1;          // K half
  const int cw   = (wv & 1) ^ kh;    // cell
  const int bid  = blockIdx.x;
  const int jg   = bid >> 3;
  const int ht   = (bid & 7)*2 + (jg & 1);   // XCD swizzle, 0..15
  const int bt   = jg >> 1;                  // 0..31 (32 rows each)

  _Float16* const AOv[2] = {AO0, AO1};
  _Float16* const AFv[2] = {AF0, AF1};

  // epilogue-compute ownership (all 256): row erow (0..31), cols enib*4..+3
  const int erow = tid >> 3, enib = tid & 7;
  // store ownership (tid>=128): tid2 -> (b_loc, oct)
  const int tid2  = tid - 128;
  const int b_loc = (tid2 >= 0) ? (tid2 >> 2) : 0, oct = tid2 & 3;
  const int m     = b_loc & 15, mtile_e = bt*2 + (b_loc >> 4);
  const int STASH = 8448;

  int ntg_[8];
  #pragma unroll
  for (int tt = 0; tt < 8; tt++) ntg_[tt] = (tt>>1)*32 + ht*2 + (tt&1);

  float c1s[4], c2s[4];
  #pragma unroll
  for (int i = 0; i < 4; i++) { c1s[i] = 0.f; c2s[i] = 0.f; }

  for (int r = 0; r < 162; r++) {
    const bool p1 = r < 129;
    const int  f  = r - 129;
    const int  wp = p1 ? (r & 1) : (f & 1);   // write parity
    const int  rp = wp ^ 1;                   // read parity
    const _Float16* A1 = p1 ? AOv[rp] : AFv[rp];
    const _Float16* A2 = AOv[rp];
    const bool skip1 = (r == 128 || r == 161);
    const bool skip2 = (r == 0   || r == 129);

    // ---- this wave's GEMM ----
    const _Float16* Ac = cw ? A2 : A1;
    const _Float16* Bc = cw ? W2 : (p1 ? W1 : W2);
    const int wk   = cw ? 32 : (p1 ? 16 : 32);
    const int half = cw ? 16 : (p1 ? 8 : 16);
    const int ch0  = kh * half;

    v4f acc[2][8];
    #pragma unroll
    for (int i2 = 0; i2 < 2; i2++)
      #pragma unroll
      for (int tt = 0; tt < 8; tt++) acc[i2][tt] = (v4f){0,0,0,0};

    uint aoff[2];
    #pragma unroll
    for (int i2 = 0; i2 < 2; i2++)
      aoff[i2] = (uint)(((bt*2 + i2)*32 + ch0)*512 + lane*8);
    uint boff[8];
    #pragma unroll
    for (int tt = 0; tt < 8; tt++)
      boff[tt] = (uint)((ntg_[tt]*wk + ch0)*512 + lane*8);

    #pragma unroll 4
    for (int cc = 0; cc < half; cc++) {
      v8h av[2];
      #pragma unroll
      for (int i2 = 0; i2 < 2; i2++)
        av[i2] = ld_frag_dev(Ac, aoff[i2] + cc*512);
      #pragma unroll
      for (int tt = 0; tt < 8; tt++) {
        v8h bv = *(const v8h*)(Bc + boff[tt] + cc*512);
        #pragma unroll
        for (int i2 = 0; i2 < 2; i2++)
          acc[i2][tt] = __builtin_amdgcn_mfma_f32_16x16x32_f16(av[i2], bv, acc[i2][tt], 0, 0, 0);
      }
    }

    // ---- K-reduce: kh=1 waves dump, kh=0 waves combine ----
    const int rbase = cw * 4096;
    if (kh) {
      #pragma unroll
      for (int i2 = 0; i2 < 2; i2++)
        #pragma unroll
        for (int tt = 0; tt < 8; tt++)
          *(v4f*)&lred[rbase + ((i2*8 + tt)*64 + lane)*4] = acc[i2][tt];
    }
    __syncthreads();
    if (!kh) {
      #pragma unroll
      for (int i2 = 0; i2 < 2; i2++)
        #pragma unroll
        for (int tt = 0; tt < 8; tt++)
          acc[i2][tt] += *(const v4f*)&lred[rbase + ((i2*8 + tt)*64 + lane)*4];
    }
    __syncthreads();

    // ---- scatter cell1 into gred (stride 132) by wave wv0 ----
    if (!kh && cw == 0) {
      #pragma unroll
      for (int i2 = 0; i2 < 2; i2++)
        #pragma unroll
        for (int tt = 0; tt < 8; tt++) {
          int row = i2*16 + quad*4;
          int col = tt*16 + lc;
          #pragma unroll
          for (int rr = 0; rr < 4; rr++) lred[(row + rr)*132 + col] = acc[i2][tt][rr];
        }
    }
    __syncthreads();

    // ================= epilogue cell1 (all 256 threads) =================
    {
      const float* bsx = p1 ? bs1 : bs2;
      float g[4][4];
      #pragma unroll
      for (int g4 = 0; g4 < 4; g4++) {
        v4f gv = *(const v4f*)&lred[erow*132 + g4*32 + enib*4];
        v4f bv = *(const v4f*)&bsx[g4*512 + ht*32 + enib*4];
        #pragma unroll
        for (int j = 0; j < 4; j++) g[g4][j] = gv[j] + bv[j];
      }
      if (p1 && r < 128) {             // + x @ Wih1^T (K=4, exact fp32)
        const v4f xv = *(const v4f*)(x + ((size_t)r*1024 + bt*32 + erow)*4);
        #pragma unroll
        for (int g4 = 0; g4 < 4; g4++)
          #pragma unroll
          for (int j = 0; j < 4; j++) {
            int hh = ht*32 + enib*4 + j;
            const v4f w = *(const v4f*)(Wih1 + (size_t)(g4*512 + hh)*4);
            g[g4][j] += xv[0]*w[0] + xv[1]*w[1] + xv[2]*w[2] + xv[3]*w[3];
          }
      }
      if (!skip1) {
        v4f hf;
        #pragma unroll
        for (int j = 0; j < 4; j++) {
          float ig = sigmoidf_(g[0][j]), fg = sigmoidf_(g[1][j]);
          float gg = tanhf_(g[2][j]),    og = sigmoidf_(g[3][j]);
          float c = fg*c1s[j] + ig*gg;
          c1s[j] = c;
          hf[j] = og * tanhf_(c);
        }
        *(v4f*)&lred[STASH + erow*36 + enib*4] = hf;
      }
    }
    __syncthreads();

    // ---- concurrent: store h1 (tid>=128, from stash) + scatter cell2 (wv1) ----
    if (tid >= 128 && !skip1) {
      v4f h0 = *(const v4f*)&lred[STASH + b_loc*36 + oct*8];
      v4f h1 = *(const v4f*)&lred[STASH + b_loc*36 + oct*8 + 4];
      union { _Float16 h8[8]; unsigned long long u[2]; } hu;
      #pragma unroll
      for (int j = 0; j < 4; j++) { hu.h8[j] = (_Float16)h0[j]; hu.h8[4+j] = (_Float16)h1[j]; }
      auto st16 = [&](_Float16* bp, int chunk) {
        unsigned long long* p = (unsigned long long*)
          (bp + (((size_t)(mtile_e*32 + chunk)) << 9) + (oct*16 + m)*8);
        __hip_atomic_store(p,     hu.u[0], __ATOMIC_RELAXED, __HIP_MEMORY_SCOPE_AGENT);
        __hip_atomic_store(p + 1, hu.u[1], __ATOMIC_RELAXED, __HIP_MEMORY_SCOPE_AGENT);
      };
      if (p1) {
        st16(AOv[wp], ht);
        if (r == 127) st16(AFv[1], 16 + ht);   // h1(127) for f=0's h1f-GEMM
      } else {
        st16(AFv[wp], 16 + ht);
        st16(AOv[wp], ht);
      }
    }
    if (!kh && cw == 1) {              // scatter cell2 into gred (wave wv1)
      #pragma unroll
      for (int i2 = 0; i2 < 2; i2++)
        #pragma unroll
        for (int tt = 0; tt < 8; tt++) {
          int row = i2*16 + quad*4;
          int col = tt*16 + lc;
          #pragma unroll
          for (int rr = 0; rr < 4; rr++) lred[(row + rr)*132 + col] = acc[i2][tt][rr];
        }
    }
    __syncthreads();

    // ================= epilogue cell2 (all 256 threads) =================
    {
      float g[4][4];
      #pragma unroll
      for (int g4 = 0; g4 < 4; g4++) {
        v4f gv = *(const v4f*)&lred[erow*132 + g4*32 + enib*4];
        v4f bv = *(const v4f*)&bs2[g4*512 + ht*32 + enib*4];
        #pragma unroll
        for (int j = 0; j < 4; j++) g[g4][j] = gv[j] + bv[j];
      }
      if (!skip2) {
        v4f hf;
        #pragma unroll
        for (int j = 0; j < 4; j++) {
          float ig = sigmoidf_(g[0][j]), fg = sigmoidf_(g[1][j]);
          float gg = tanhf_(g[2][j]),    og = sigmoidf_(g[3][j]);
          float c = fg*c2s[j] + ig*gg;
          c2s[j] = c;
          hf[j] = og * tanhf_(c);
        }
        *(v4f*)&lred[STASH + erow*36 + enib*4] = hf;
      }
    }
    __syncthreads();

    // ---- store h2 (tid>=128) + out-projection (tid<128, phase2) ----
    if (tid >= 128 && !skip2) {
      v4f h0 = *(const v4f*)&lred[STASH + b_loc*36 + oct*8];
      v4f h1 = *(const v4f*)&lred[STASH + b_loc*36 + oct*8 + 4];
      union { _Float16 h8[8]; unsigned long long u[2]; } hu;
      #pragma unroll
      for (int j = 0; j < 4; j++) { hu.h8[j] = (_Float16)h0[j]; hu.h8[4+j] = (_Float16)h1[j]; }
      auto st16 = [&](_Float16* bp, int chunk) {
        unsigned long long* p = (unsigned long long*)
          (bp + (((size_t)(mtile_e*32 + chunk)) << 9) + (oct*16 + m)*8);
        __hip_atomic_store(p,     hu.u[0], __ATOMIC_RELAXED, __HIP_MEMORY_SCOPE_AGENT);
        __hip_atomic_store(p + 1, hu.u[1], __ATOMIC_RELAXED, __HIP_MEMORY_SCOPE_AGENT);
      };
      st16(AOv[wp], 16 + ht);
      if (r == 128) { st16(AFv[0], ht); st16(AFv[1], ht); }   // tmp = h2(127)
    }
    if (tid < 128 && !p1 && r >= 130) {  // out(s) = h2f(s) @ Wl^T + bl, s = r-130
      const int s = r - 130;
      int bb = tid >> 2, o = tid & 3;
      float sa = (ht == 0) ? blv[o] : 0.f;
      const float* wl = Wl + (size_t)o*512 + ht*32;
      #pragma unroll
      for (int jj = 0; jj < 32; jj++) sa += lred[STASH + bb*36 + jj] * wl[jj];
      atomicAdd(&out[(((size_t)s*1024) + bt*32 + bb)*4 + o], sa);
    }
    __syncthreads();

    // ---- per-bt-group barrier: agent-relaxed add + relaxed poll ----
    if (tid == 0) {
      int* ctr = bar + bt*32;          // 128B-spaced counters, 32 groups
      __hip_atomic_fetch_add(ctr, 1, __ATOMIC_RELAXED, __HIP_MEMORY_SCOPE_AGENT);
      const int target = 16*(r+1);
      while (__hip_atomic_load(ctr, __ATOMIC_RELAXED, __HIP_MEMORY_SCOPE_AGENT) < target)
        __builtin_amdgcn_s_sleep(1);
    }
    __syncthreads();
  }
}

extern "C" void kernel_launch(void* const* d_in, const int* in_sizes, int n_in,
                              void* d_out, int out_size, void* d_ws, size_t ws_size,
                              hipStream_t stream) {
  const float* x    = (const float*)d_in[0];
  const float* Wih1 = (const float*)d_in[1];
  const float* Whh1 = (const float*)d_in[2];
  const float* bih1 = (const float*)d_in[3];
  const float* bhh1 = (const float*)d_in[4];
  const float* Wih2 = (const float*)d_in[5];
  const float* Whh2 = (const float*)d_in[6];
  const float* bih2 = (const float*)d_in[7];
  const float* bhh2 = (const float*)d_in[8];
  const float* Wl   = (const float*)d_in[9];
  const float* bl   = (const float*)d_in[10];

  char* ws = (char*)d_ws;
  int*      bar = (int*)(ws + OFF_BAR);
  _Float16* AO0 = (_Float16*)(ws + OFF_AO0);
  _Float16* AO1 = (_Float16*)(ws + OFF_AO1);
  _Float16* AF0 = (_Float16*)(ws + OFF_AF0);
  _Float16* AF1 = (_Float16*)(ws + OFF_AF1);
  _Float16* W1p = (_Float16*)(ws + OFF_W1);
  _Float16* W2p = (_Float16*)(ws + OFF_W2);
  float*    bs1 = (float*)(ws + OFF_B1);
  float*    bs2 = (float*)(ws + OFF_B2);

  // zero barrier + state buffers (h,c start at 0); zero out (atomic accumulation)
  hipMemsetAsync(ws, 0, (size_t)OFF_W1, stream);
  hipMemsetAsync(d_out, 0, (size_t)out_size * sizeof(float), stream);

  lstm_prep<<<2048, 256, 0, stream>>>(Whh1, Wih2, Whh2, bih1, bhh1, bih2, bhh2,
                                      W1p, W2p, bs1, bs2);
  lstm_main<<<512, 256, 0, stream>>>(x, Wih1, Wl, bl, AO0, AO1, AF0, AF1,
                                     W1p, W2p, bs1, bs2, bar, (float*)d_out);
}